// Round 6
// baseline (56.599 us; speedup 1.0000x reference)
//
#include <hip/hip_runtime.h>
#include <math.h>

#define KDIM 32
#define MDIM 256
#define NDIM 2048
#define Z_TOL 1e-6f   // removal threshold (reference semantics)
#define W_TOL 1e-3f   // re-add threshold (hysteresis: kills z/w deadband cycling,
                      // since w_j = d_j*z_j with d_j <= max diag(AtA) ~ 330 < 1000)

// ---------------- helpers ----------------
__device__ __forceinline__ float lane_bcast(float x, int lane) {
  return __int_as_float(__builtin_amdgcn_readlane(__float_as_int(x), lane));
}
__device__ __forceinline__ float rcp_newton(float x) {
  float r;
  asm("v_rcp_f32 %0, %1" : "=v"(r) : "v"(x));
  r = r * (2.0f - x * r);  // one Newton step (shared LU only)
  return r;
}
__device__ __forceinline__ float rcp_fast(float x) {
  float r;
  asm("v_rcp_f32 %0, %1" : "=v"(r) : "v"(x));
  return r;  // ~1 ulp; fine vs 3e-3 threshold (kappa(AtA) ~ 56)
}

// ---------------- AtA partials: 8 blocks, each reduces 32 rows of A ------------
// part[g][i*32+j] = sum_{m in chunk g} A[m,i]*A[m,j].  No atomics (deterministic).
__global__ __launch_bounds__(1024) void ata_partial(const float* __restrict__ A,
                                                    float* __restrict__ part) {
  __shared__ float As[32 * KDIM];  // 4 KB slice
  const int t = threadIdx.x, g = blockIdx.x;
  As[t] = A[g * 32 * KDIM + t];  // 1024 floats, coalesced
  __syncthreads();
  const int i = t >> 5, j = t & 31;
  float acc = 0.f;
#pragma unroll
  for (int mm = 0; mm < 32; ++mm)
    acc = fmaf(As[mm * KDIM + i], As[mm * KDIM + j], acc);  // bcast + consecutive: conflict-free
  part[g * 1024 + t] = acc;
}

// ---------------- sum partials -> AtA; LU-factor with inverted diagonal --------
// LU packing: multipliers below diag, U above, and 1/U_jj (Newton) ON the diag.
__global__ __launch_bounds__(64) void lu_kernel(const float* __restrict__ part,
                                                float* __restrict__ AtA,
                                                float* __restrict__ LU) {
  __shared__ float AtAs[KDIM * 33];  // padded
  const int l = threadIdx.x;
  const int r = l & 31;
  // sum 8 partials; thread handles 4 float4 chunks, fully coalesced
#pragma unroll
  for (int q4 = 0; q4 < 4; ++q4) {
    const int f4 = q4 * 64 + l;  // float4 index within 1024-float matrix
    float4 s = {0.f, 0.f, 0.f, 0.f};
#pragma unroll
    for (int g = 0; g < 8; ++g) {
      const float4 v = reinterpret_cast<const float4*>(part)[g * 256 + f4];
      s.x += v.x; s.y += v.y; s.z += v.z; s.w += v.w;
    }
    reinterpret_cast<float4*>(AtA)[f4] = s;
    const int e = f4 * 4, row = e >> 5, col = e & 31;
    AtAs[row * 33 + col + 0] = s.x;
    AtAs[row * 33 + col + 1] = s.y;
    AtAs[row * 33 + col + 2] = s.z;
    AtAs[row * 33 + col + 3] = s.w;
  }
  __syncthreads();
  float m[KDIM];
#pragma unroll
  for (int c = 0; c < KDIM; ++c) m[c] = AtAs[r * 33 + c];  // (r+c)%32: conflict-free
#pragma unroll
  for (int j = 0; j < KDIM; ++j) {
    const float inv = rcp_newton(lane_bcast(m[j], j));
    if (j < KDIM - 1) {
      const float f = (r > j) ? m[j] * inv : 0.f;
#pragma unroll
      for (int c = j + 1; c < KDIM; ++c) m[c] = fmaf(-f, lane_bcast(m[c], j), m[c]);
      if (r > j) m[j] = f;  // pack multiplier
    }
    if (r == j) m[j] = inv;  // pack inverted diagonal
  }
  if (l < 32) {
#pragma unroll
    for (int c = 0; c < KDIM; ++c) LU[r * KDIM + c] = m[c];
  }
}

// ---------------- per-column NNLS (fused Atb), one wave per column -------------
// Lane l owns row r=l&31; hi half mirrors lo so all branches are wave-uniform.
// Solver: block principal pivoting + Murty least-index safeguard + hysteresis,
// all-register GE solves with readlane broadcasts. No LDS.
__global__ __launch_bounds__(64, 2) void nnls_kernel(const float* __restrict__ A,
                                                     const float* __restrict__ AtA_g,
                                                     const float* __restrict__ LU_g,
                                                     const float* __restrict__ X,
                                                     float* __restrict__ S) {
  const int l = threadIdx.x;
  const int r = l & 31;
  const int n = blockIdx.x;

  // ---- phase 1: Atb = A^T X[:, n] ----
  float x4[4];
#pragma unroll
  for (int q = 0; q < 4; ++q) x4[q] = X[(q * 64 + l) * NDIM + n];
  float cur[KDIM];
#pragma unroll
  for (int k = 0; k < KDIM; ++k) cur[k] = 0.f;
#pragma unroll
  for (int q = 0; q < 4; ++q) {
    const int m = q * 64 + l;
#pragma unroll
    for (int qq = 0; qq < 8; ++qq) {
      const float4 a4 = reinterpret_cast<const float4*>(A + m * KDIM)[qq];
      cur[4 * qq + 0] = fmaf(a4.x, x4[q], cur[4 * qq + 0]);
      cur[4 * qq + 1] = fmaf(a4.y, x4[q], cur[4 * qq + 1]);
      cur[4 * qq + 2] = fmaf(a4.z, x4[q], cur[4 * qq + 2]);
      cur[4 * qq + 3] = fmaf(a4.w, x4[q], cur[4 * qq + 3]);
    }
  }
  // butterfly: sum over lanes, element k -> lane k (hi half mirrored by off=32)
#pragma unroll
  for (int k = 0; k < KDIM; ++k) cur[k] += __shfl_xor(cur[k], 32);
#pragma unroll
  for (int o = 16; o >= 1; o >>= 1) {
#pragma unroll
    for (int i = 0; i < o; ++i) {
      const bool hi = (l & o) != 0;
      const float a = cur[i], b = cur[i + o];
      const float mine = hi ? b : a;
      const float send = hi ? a : b;
      cur[i] = mine + __shfl_xor(send, o);
    }
  }
  const float atb = cur[0];  // = Atb[r], mirrored in hi half

  // ---- phase 2: load shared AtA row + LU row ----
  float ata[KDIM], lu[KDIM];
#pragma unroll
  for (int q = 0; q < KDIM / 4; ++q) {
    const float4 v = reinterpret_cast<const float4*>(AtA_g + r * KDIM)[q];
    ata[4 * q + 0] = v.x; ata[4 * q + 1] = v.y; ata[4 * q + 2] = v.z; ata[4 * q + 3] = v.w;
    const float4 u = reinterpret_cast<const float4*>(LU_g + r * KDIM)[q];
    lu[4 * q + 0] = u.x; lu[4 * q + 1] = u.y; lu[4 * q + 2] = u.z; lu[4 * q + 3] = u.w;
  }

  // masked solve: (AtA o PP^T + diag(1-P)) z = P o Atb, registers + readlane only.
  // Pivot reciprocal computed once (plain v_rcp) and stored in the diag slot so
  // back-substitution reuses it.
  auto solve = [&](unsigned int Pm) -> float {
    const bool actl = (Pm >> r) & 1u;
    float m[KDIM];
#pragma unroll
    for (int c = 0; c < KDIM; ++c) {
      const bool actc = (Pm >> c) & 1u;
      m[c] = (actl && actc) ? ata[c] : ((r == c) ? 1.f : 0.f);
    }
    float rhs = actl ? atb : 0.f;
#pragma unroll
    for (int j = 0; j < KDIM; ++j) {
      if ((Pm >> j) & 1u) {
        const float inv = rcp_fast(lane_bcast(m[j], j));
        if (j < KDIM - 1) {
          const float f = (r > j) ? m[j] * inv : 0.f;
#pragma unroll
          for (int c = j + 1; c < KDIM; ++c) m[c] = fmaf(-f, lane_bcast(m[c], j), m[c]);
          rhs = fmaf(-f, lane_bcast(rhs, j), rhs);
        }
        if (r == j) m[j] = inv;  // stash reciprocal for back-sub
      }
    }
    float zz = 0.f;
#pragma unroll
    for (int j = KDIM - 1; j >= 0; --j) {
      if ((Pm >> j) & 1u) {
        const float xj = lane_bcast(rhs, j) * lane_bcast(m[j], j);  // rhs * (1/diag)
        if (r == j) zz = xj;
        if (r < j) rhs = fmaf(-m[j], xj, rhs);
      }
    }
    return zz;
  };

  unsigned int P;
  float z;
  {
    const unsigned long long b0 = __ballot(atb > Z_TOL);
    const unsigned int P0 = (unsigned int)(b0 & 0xffffffffull);
    if (P0 == 0xffffffffu) {
      // shared-LU fast path: substitutions only, no divisions at all
      P = P0;
      float rhs = atb;
#pragma unroll
      for (int j = 0; j < KDIM - 1; ++j) {
        const float fj = (r > j) ? lu[j] : 0.f;
        rhs = fmaf(-fj, lane_bcast(rhs, j), rhs);
      }
      z = 0.f;
#pragma unroll
      for (int j = KDIM - 1; j >= 0; --j) {
        const float xj = lane_bcast(rhs, j) * lane_bcast(lu[j], j);  // diag pre-inverted
        if (r == j) z = xj;
        const float uj = (r < j) ? lu[j] : 0.f;
        rhs = fmaf(-uj, xj, rhs);
      }
    } else {
      P = 0u;
      z = 0.f;
    }
  }

  // block principal pivoting with Murty least-index safeguard + hysteresis
  int ninf_best = 1000, budget = 3;
  for (int it = 0; it < 64; ++it) {
    const bool act = (P >> r) & 1u;
    const float zm = act ? z : 0.f;
    float w = atb;
#pragma unroll
    for (int c = 0; c < KDIM; ++c) w = fmaf(-ata[c], lane_bcast(zm, c), w);
    const unsigned long long bb = __ballot(act && (z <= Z_TOL));
    const unsigned long long vb = __ballot((!act) && (w > W_TOL));
    const unsigned int bad = (unsigned int)(bb & 0xffffffffull);
    const unsigned int viol = (unsigned int)(vb & 0xffffffffull);
    const unsigned int u = bad | viol;
    if (u == 0u) break;  // hysteresis-KKT satisfied (uniform)
    const int ninf = __popc(u);
    bool useblock;
    if (ninf < ninf_best) { ninf_best = ninf; budget = 3; useblock = true; }
    else if (budget > 0) { --budget; useblock = true; }
    else { useblock = false; }
    if (useblock) {
      P = (P & ~bad) | viol;
    } else {
      const int j = __ffs(u) - 1;  // Murty: least-index single flip
      P ^= (1u << j);
    }
    z = solve(P);
  }

  if (l < KDIM) S[r * NDIM + n] = ((P >> r) & 1u) ? z : 0.f;
}

extern "C" void kernel_launch(void* const* d_in, const int* in_sizes, int n_in,
                              void* d_out, int out_size, void* d_ws, size_t ws_size,
                              hipStream_t stream) {
  const float* X = (const float*)d_in[0];  // [256, 2048]
  const float* A = (const float*)d_in[1];  // [256, 32]
  float* S = (float*)d_out;                // [32, 2048]
  float* AtA = (float*)d_ws;               // 1024 floats
  float* LU = AtA + KDIM * KDIM;           // 1024 floats
  float* part = LU + KDIM * KDIM;          // 8*1024 floats

  ata_partial<<<8, 1024, 0, stream>>>(A, part);
  lu_kernel<<<1, 64, 0, stream>>>(part, AtA, LU);
  nnls_kernel<<<NDIM, 64, 0, stream>>>(A, AtA, LU, X, S);
}